// Round 1
// baseline (2196.279 us; speedup 1.0000x reference)
//
#include <hip/hip_runtime.h>

#define N_NODES 100000
#define N_EDGES 3200000
#define F_IN 512
#define HIDDEN 64
#define N_CLASSES 47
#define K_HOPS 10
#define ALPHA 0.1f

// ---------------------------------------------------------------------------
// CSR build: histogram of target (col) degrees
__global__ __launch_bounds__(256) void hist_kernel(const int* __restrict__ col,
                                                   int* __restrict__ cnt) {
    int i = blockIdx.x * 256 + threadIdx.x;
    if (i < N_EDGES) atomicAdd(&cnt[col[i]], 1);
}

// dis[i] = rsqrt(deg_col[i] + 1)  (the +1 is the self-loop)
__global__ __launch_bounds__(256) void dis_kernel(const int* __restrict__ cnt,
                                                  float* __restrict__ dis) {
    int i = blockIdx.x * 256 + threadIdx.x;
    if (i < N_NODES) dis[i] = rsqrtf((float)cnt[i] + 1.0f);
}

// Single-block exclusive scan of cnt -> colptr[0..N], carry kept in registers.
__global__ __launch_bounds__(1024) void scan_kernel(const int* __restrict__ cnt,
                                                    int* __restrict__ colptr) {
    __shared__ int tile[1024];
    int carry = 0;
    if (threadIdx.x == 0) colptr[0] = 0;
    for (int base = 0; base < N_NODES; base += 1024) {
        int i = base + threadIdx.x;
        int v = (i < N_NODES) ? cnt[i] : 0;
        tile[threadIdx.x] = v;
        __syncthreads();
        for (int off = 1; off < 1024; off <<= 1) {
            int t = (threadIdx.x >= off) ? tile[threadIdx.x - off] : 0;
            __syncthreads();
            tile[threadIdx.x] += t;
            __syncthreads();
        }
        if (i < N_NODES) colptr[i + 1] = carry + tile[threadIdx.x];
        carry += tile[1023];
        __syncthreads();   // protect tile before next-iteration overwrite
    }
}

// Scatter edges into CSR slots (cursor pre-copied from colptr)
__global__ __launch_bounds__(256) void fill_kernel(const int* __restrict__ row,
                                                   const int* __restrict__ col,
                                                   int* __restrict__ cursor,
                                                   int* __restrict__ csr_row) {
    int e = blockIdx.x * 256 + threadIdx.x;
    if (e < N_EDGES) {
        int c = col[e];
        int slot = atomicAdd(&cursor[c], 1);
        csr_row[slot] = row[e];
    }
}

// ---------------------------------------------------------------------------
// h0 = relu(x @ W_embed + b_embed) : [N,512]@[512,64]
// Thread = one row; W staged in LDS in 128-k chunks; LDS reads are wave-
// broadcast (same address all lanes) -> no bank conflicts.
__global__ __launch_bounds__(256) void embed_kernel(const float* __restrict__ x,
                                                    const float* __restrict__ W,
                                                    const float* __restrict__ b,
                                                    float* __restrict__ h0) {
    __shared__ float Wl[128 * 64];   // 32 KB chunk
    int row = blockIdx.x * 256 + threadIdx.x;
    float acc[64];
#pragma unroll
    for (int c = 0; c < 64; ++c) acc[c] = 0.0f;

    for (int kc = 0; kc < F_IN; kc += 128) {
        __syncthreads();
        // stage W[kc:kc+128, :] -> 8192 floats by 256 threads (float4)
        for (int i = threadIdx.x * 4; i < 128 * 64; i += 256 * 4) {
            *reinterpret_cast<float4*>(Wl + i) =
                *reinterpret_cast<const float4*>(W + (size_t)kc * 64 + i);
        }
        __syncthreads();
        if (row < N_NODES) {
            const float* xr = x + (size_t)row * F_IN + kc;
            for (int k = 0; k < 128; k += 4) {
                float4 xv = *reinterpret_cast<const float4*>(xr + k);
#pragma unroll
                for (int kk = 0; kk < 4; ++kk) {
                    float xs = (&xv.x)[kk];
#pragma unroll
                    for (int c = 0; c < 64; c += 4) {
                        float4 wv = *reinterpret_cast<const float4*>(Wl + (k + kk) * 64 + c);
                        acc[c]     += xs * wv.x;
                        acc[c + 1] += xs * wv.y;
                        acc[c + 2] += xs * wv.z;
                        acc[c + 3] += xs * wv.w;
                    }
                }
            }
        }
    }
    if (row < N_NODES) {
#pragma unroll
        for (int c = 0; c < 64; c += 4) {
            float4 bv = *reinterpret_cast<const float4*>(b + c);
            float4 o;
            o.x = fmaxf(acc[c]     + bv.x, 0.0f);
            o.y = fmaxf(acc[c + 1] + bv.y, 0.0f);
            o.z = fmaxf(acc[c + 2] + bv.z, 0.0f);
            o.w = fmaxf(acc[c + 3] + bv.w, 0.0f);
            *reinterpret_cast<float4*>(h0 + (size_t)row * HIDDEN + c) = o;
        }
    }
}

// ---------------------------------------------------------------------------
// One hop: hout[n] = 0.9 * (dis[n]^2*hin[n] + sum_e dis[row_e]*dis[n]*hin[row_e])
//                  + 0.1 * h0[n]
// One wave per node. Lane = 16*edge_slot + feature_quad: each gather moves
// 64 lanes x 16 B = 1 KB covering 4 edges. Cross-slot reduce via shfl_xor.
__global__ __launch_bounds__(256) void hop_kernel(const float* __restrict__ hin,
                                                  const float* __restrict__ h0,
                                                  const int* __restrict__ colptr,
                                                  const int* __restrict__ rows,
                                                  const float* __restrict__ dis,
                                                  float* __restrict__ hout) {
    int wid  = (blockIdx.x * 256 + threadIdx.x) >> 6;   // node
    int lane = threadIdx.x & 63;
    int grp  = lane >> 4;            // edge slot 0..3
    int f4   = (lane & 15) << 2;     // feature base

    int beg = colptr[wid];
    int end = colptr[wid + 1];
    float dn = dis[wid];

    float4 acc = make_float4(0.f, 0.f, 0.f, 0.f);
    if (grp == 0) {  // self loop, norm = dn*dn
        float4 hv = *reinterpret_cast<const float4*>(hin + (size_t)wid * HIDDEN + f4);
        float w = dn * dn;
        acc.x = w * hv.x; acc.y = w * hv.y; acc.z = w * hv.z; acc.w = w * hv.w;
    }
    for (int e = beg + grp; e < end; e += 4) {
        int r = rows[e];
        float w = dis[r] * dn;
        float4 hv = *reinterpret_cast<const float4*>(hin + (size_t)r * HIDDEN + f4);
        acc.x += w * hv.x; acc.y += w * hv.y; acc.z += w * hv.z; acc.w += w * hv.w;
    }
    // reduce the 4 edge slots (lanes L, L^16, L^32, L^48)
    acc.x += __shfl_xor(acc.x, 16); acc.y += __shfl_xor(acc.y, 16);
    acc.z += __shfl_xor(acc.z, 16); acc.w += __shfl_xor(acc.w, 16);
    acc.x += __shfl_xor(acc.x, 32); acc.y += __shfl_xor(acc.y, 32);
    acc.z += __shfl_xor(acc.z, 32); acc.w += __shfl_xor(acc.w, 32);

    if (grp == 0) {
        float4 h0v = *reinterpret_cast<const float4*>(h0 + (size_t)wid * HIDDEN + f4);
        float4 o;
        o.x = (1.0f - ALPHA) * acc.x + ALPHA * h0v.x;
        o.y = (1.0f - ALPHA) * acc.y + ALPHA * h0v.y;
        o.z = (1.0f - ALPHA) * acc.z + ALPHA * h0v.z;
        o.w = (1.0f - ALPHA) * acc.w + ALPHA * h0v.w;
        *reinterpret_cast<float4*>(hout + (size_t)wid * HIDDEN + f4) = o;
    }
}

// ---------------------------------------------------------------------------
// logits = h @ W_pred + b_pred; out = [log_softmax | logits | softmax] flat
__global__ __launch_bounds__(256) void pred_kernel(const float* __restrict__ h,
                                                   const float* __restrict__ Wp,
                                                   const float* __restrict__ bp,
                                                   float* __restrict__ out) {
    __shared__ float Wl[HIDDEN * N_CLASSES];
    __shared__ float bl[N_CLASSES];
    for (int i = threadIdx.x; i < HIDDEN * N_CLASSES; i += 256) Wl[i] = Wp[i];
    if (threadIdx.x < N_CLASSES) bl[threadIdx.x] = bp[threadIdx.x];
    __syncthreads();

    int node = blockIdx.x * 256 + threadIdx.x;
    if (node >= N_NODES) return;

    float acc[N_CLASSES];
#pragma unroll
    for (int c = 0; c < N_CLASSES; ++c) acc[c] = bl[c];

    const float* hr = h + (size_t)node * HIDDEN;
    for (int k = 0; k < HIDDEN; k += 4) {
        float4 hv = *reinterpret_cast<const float4*>(hr + k);
#pragma unroll
        for (int kk = 0; kk < 4; ++kk) {
            float hs = (&hv.x)[kk];
#pragma unroll
            for (int c = 0; c < N_CLASSES; ++c)
                acc[c] += hs * Wl[(k + kk) * N_CLASSES + c];
        }
    }
    float mx = acc[0];
#pragma unroll
    for (int c = 1; c < N_CLASSES; ++c) mx = fmaxf(mx, acc[c]);
    float sum = 0.0f;
    float ex[N_CLASSES];
#pragma unroll
    for (int c = 0; c < N_CLASSES; ++c) { ex[c] = expf(acc[c] - mx); sum += ex[c]; }
    float lse = mx + logf(sum);
    float inv = 1.0f / sum;

    size_t o1 = (size_t)node * N_CLASSES;
#pragma unroll
    for (int c = 0; c < N_CLASSES; ++c) out[o1 + c] = acc[c] - lse;
#pragma unroll
    for (int c = 0; c < N_CLASSES; ++c) out[(size_t)N_NODES * N_CLASSES + o1 + c] = acc[c];
#pragma unroll
    for (int c = 0; c < N_CLASSES; ++c) out[(size_t)2 * N_NODES * N_CLASSES + o1 + c] = ex[c] * inv;
}

// ---------------------------------------------------------------------------
extern "C" void kernel_launch(void* const* d_in, const int* in_sizes, int n_in,
                              void* d_out, int out_size, void* d_ws, size_t ws_size,
                              hipStream_t stream) {
    const float* x       = (const float*)d_in[0];
    const int*   ei      = (const int*)d_in[1];    // [2, E]: rows then cols
    const float* W_embed = (const float*)d_in[2];
    const float* b_embed = (const float*)d_in[3];
    const float* W_pred  = (const float*)d_in[4];
    const float* b_pred  = (const float*)d_in[5];
    float* out = (float*)d_out;

    char* ws = (char*)d_ws;
    size_t off = 0;
    auto alloc = [&](size_t bytes) -> void* {
        void* p = ws + off;
        off += (bytes + 255) & ~(size_t)255;
        return p;
    };
    float* h0      = (float*)alloc((size_t)N_NODES * HIDDEN * 4);
    float* hA      = (float*)alloc((size_t)N_NODES * HIDDEN * 4);
    float* hB      = (float*)alloc((size_t)N_NODES * HIDDEN * 4);
    float* dis     = (float*)alloc((size_t)N_NODES * 4);
    int*   cnt     = (int*)  alloc((size_t)N_NODES * 4);
    int*   colptr  = (int*)  alloc((size_t)(N_NODES + 1) * 4);
    int*   cursor  = (int*)  alloc((size_t)N_NODES * 4);
    int*   csr_row = (int*)  alloc((size_t)N_EDGES * 4);

    const int* e_row = ei;
    const int* e_col = ei + N_EDGES;

    // --- CSR build ---
    hipMemsetAsync(cnt, 0, (size_t)N_NODES * 4, stream);
    hist_kernel<<<(N_EDGES + 255) / 256, 256, 0, stream>>>(e_col, cnt);
    dis_kernel<<<(N_NODES + 255) / 256, 256, 0, stream>>>(cnt, dis);
    scan_kernel<<<1, 1024, 0, stream>>>(cnt, colptr);
    hipMemcpyAsync(cursor, colptr, (size_t)N_NODES * 4, hipMemcpyDeviceToDevice, stream);
    fill_kernel<<<(N_EDGES + 255) / 256, 256, 0, stream>>>(e_row, e_col, cursor, csr_row);

    // --- embed ---
    embed_kernel<<<(N_NODES + 255) / 256, 256, 0, stream>>>(x, W_embed, b_embed, h0);

    // --- 10 propagation hops, ping-pong ---
    const float* hin = h0;
    float* bufs[2] = {hA, hB};
    for (int k = 0; k < K_HOPS; ++k) {
        float* ho = bufs[k & 1];
        hop_kernel<<<N_NODES / 4, 256, 0, stream>>>(hin, h0, colptr, csr_row, dis, ho);
        hin = ho;
    }

    // --- prediction head + softmax outputs ---
    pred_kernel<<<(N_NODES + 255) / 256, 256, 0, stream>>>(hin, W_pred, b_pred, out);
}

// Round 2
// 1719.783 us; speedup vs baseline: 1.2771x; 1.2771x over previous
//
#include <hip/hip_runtime.h>

#define N_NODES 100000
#define N_EDGES 3200000
#define F_IN 512
#define HIDDEN 64
#define N_CLASSES 47
#define K_HOPS 10
#define ALPHA 0.1f

#define NBUCK 1563            // ceil(N_NODES / 64) buckets of 64 node ids
#define NGRP 8                // sub-buckets (≈ per-XCD write streams)
#define SUBCAP 448            // capacity per (group,bucket); mean 256, +12 sigma
#define CSRCAP (NGRP * SUBCAP) // csr_row slots reserved per bucket (gapped CSR)

// ---------------------------------------------------------------------------
// Partition edges into (group, bucket) append streams.
// bucket = col >> 6 ; packed word = (col & 63) << 20 | row   (row < 2^17)
// group = blockIdx & 7 ~ XCD identity -> each append stream is written by one
// L2 only -> cache lines fill completely before writeback (no write amp).
__global__ __launch_bounds__(256) void partition_kernel(const int* __restrict__ row,
                                                        const int* __restrict__ col,
                                                        int* __restrict__ bcur,
                                                        unsigned int* __restrict__ bpairs) {
    int e = blockIdx.x * 256 + threadIdx.x;
    if (e >= N_EDGES) return;
    int g = blockIdx.x & (NGRP - 1);
    int c = col[e];
    int b = c >> 6;
    int slot = atomicAdd(&bcur[g * NBUCK + b], 1);
    if (slot < SUBCAP) {
        bpairs[((size_t)g * NBUCK + b) * SUBCAP + slot] =
            (unsigned int)row[e] | ((unsigned int)(c & 63) << 20);
    }
}

// ---------------------------------------------------------------------------
// One block per bucket: count 64 local degrees in LDS, local scan, write
// colbeg/colend/dis and scatter rows into this bucket's contiguous csr region.
__global__ __launch_bounds__(256) void build_kernel(const unsigned int* __restrict__ bpairs,
                                                    const int* __restrict__ bcur,
                                                    int* __restrict__ colbeg,
                                                    int* __restrict__ colend,
                                                    float* __restrict__ dis,
                                                    int* __restrict__ csr_row) {
    __shared__ int lcnt[64];
    __shared__ int lcur[64];
    int b = blockIdx.x;
    int tid = threadIdx.x;
    if (tid < 64) lcnt[tid] = 0;
    __syncthreads();

    // phase 1: count local degrees
    for (int g = 0; g < NGRP; ++g) {
        int cg = bcur[g * NBUCK + b];
        if (cg > SUBCAP) cg = SUBCAP;
        const unsigned int* seg = bpairs + ((size_t)g * NBUCK + b) * SUBCAP;
        for (int i = tid; i < cg; i += 256)
            atomicAdd(&lcnt[seg[i] >> 20], 1);
    }
    __syncthreads();

    // local exclusive scan (64 values, serial on t0 is cheap across 1563 blocks)
    if (tid == 0) {
        int run = b * CSRCAP;
        for (int j = 0; j < 64; ++j) { lcur[j] = run; run += lcnt[j]; }
    }
    __syncthreads();
    if (tid < 64) {
        int node = b * 64 + tid;
        if (node < N_NODES) {
            colbeg[node] = lcur[tid];
            colend[node] = lcur[tid] + lcnt[tid];
            dis[node] = rsqrtf((float)lcnt[tid] + 1.0f);  // +1 = self loop
        }
    }
    __syncthreads();

    // phase 2: scatter rows into the bucket's 14KB csr region (L1-local)
    for (int g = 0; g < NGRP; ++g) {
        int cg = bcur[g * NBUCK + b];
        if (cg > SUBCAP) cg = SUBCAP;
        const unsigned int* seg = bpairs + ((size_t)g * NBUCK + b) * SUBCAP;
        for (int i = tid; i < cg; i += 256) {
            unsigned int p = seg[i];
            int slot = atomicAdd(&lcur[p >> 20], 1);
            csr_row[slot] = (int)(p & 0xFFFFFu);
        }
    }
}

// ---------------------------------------------------------------------------
// h0 = relu(x @ W_embed + b_embed); also g0 = dis * h0 (rescaled features).
__global__ __launch_bounds__(256) void embed_kernel(const float* __restrict__ x,
                                                    const float* __restrict__ W,
                                                    const float* __restrict__ b,
                                                    const float* __restrict__ dis,
                                                    float* __restrict__ h0,
                                                    float* __restrict__ g0) {
    __shared__ float Wl[128 * 64];   // 32 KB chunk
    int row = blockIdx.x * 256 + threadIdx.x;
    float acc[64];
#pragma unroll
    for (int c = 0; c < 64; ++c) acc[c] = 0.0f;

    for (int kc = 0; kc < F_IN; kc += 128) {
        __syncthreads();
        for (int i = threadIdx.x * 4; i < 128 * 64; i += 256 * 4) {
            *reinterpret_cast<float4*>(Wl + i) =
                *reinterpret_cast<const float4*>(W + (size_t)kc * 64 + i);
        }
        __syncthreads();
        if (row < N_NODES) {
            const float* xr = x + (size_t)row * F_IN + kc;
            for (int k = 0; k < 128; k += 4) {
                float4 xv = *reinterpret_cast<const float4*>(xr + k);
#pragma unroll
                for (int kk = 0; kk < 4; ++kk) {
                    float xs = (&xv.x)[kk];
#pragma unroll
                    for (int c = 0; c < 64; c += 4) {
                        float4 wv = *reinterpret_cast<const float4*>(Wl + (k + kk) * 64 + c);
                        acc[c]     += xs * wv.x;
                        acc[c + 1] += xs * wv.y;
                        acc[c + 2] += xs * wv.z;
                        acc[c + 3] += xs * wv.w;
                    }
                }
            }
        }
    }
    if (row < N_NODES) {
        float dn = dis[row];
#pragma unroll
        for (int c = 0; c < 64; c += 4) {
            float4 bv = *reinterpret_cast<const float4*>(b + c);
            float4 o, g;
            o.x = fmaxf(acc[c]     + bv.x, 0.0f);
            o.y = fmaxf(acc[c + 1] + bv.y, 0.0f);
            o.z = fmaxf(acc[c + 2] + bv.z, 0.0f);
            o.w = fmaxf(acc[c + 3] + bv.w, 0.0f);
            g.x = dn * o.x; g.y = dn * o.y; g.z = dn * o.z; g.w = dn * o.w;
            *reinterpret_cast<float4*>(h0 + (size_t)row * HIDDEN + c) = o;
            *reinterpret_cast<float4*>(g0 + (size_t)row * HIDDEN + c) = g;
        }
    }
}

// ---------------------------------------------------------------------------
// One hop on rescaled features g = dis*h:
//   S[n]    = g[n] + sum_{e: col=n} g[row_e]
//   h'[n]   = 0.9 * dis[n] * S[n] + 0.1 * h0[n]
//   out[n]  = OUT_G ? dis[n]*h'[n] : h'[n]
// One wave per node; lane = 16*edge_slot + feature_quad. Per gather: 64 lanes
// x 16 B = 1 KB covering 4 edges. No per-edge scalar loads besides rows[e].
template <bool OUT_G>
__global__ __launch_bounds__(256) void hop_kernel(const float* __restrict__ gin,
                                                  const float* __restrict__ h0,
                                                  const int* __restrict__ colbeg,
                                                  const int* __restrict__ colend,
                                                  const int* __restrict__ rows,
                                                  const float* __restrict__ dis,
                                                  float* __restrict__ hout) {
    int wid  = (blockIdx.x * 256 + threadIdx.x) >> 6;   // node
    int lane = threadIdx.x & 63;
    int grp  = lane >> 4;            // edge slot 0..3
    int f4   = (lane & 15) << 2;     // feature base

    int beg = colbeg[wid];
    int end = colend[wid];
    float dn = dis[wid];

    float4 acc = make_float4(0.f, 0.f, 0.f, 0.f);
    if (grp == 0) {  // self contribution: + g[n]
        acc = *reinterpret_cast<const float4*>(gin + (size_t)wid * HIDDEN + f4);
    }
    int e = beg + grp;
    for (; e + 4 < end; e += 8) {    // 2 independent gather chains
        int r0 = rows[e];
        int r1 = rows[e + 4];
        float4 v0 = *reinterpret_cast<const float4*>(gin + (size_t)r0 * HIDDEN + f4);
        float4 v1 = *reinterpret_cast<const float4*>(gin + (size_t)r1 * HIDDEN + f4);
        acc.x += v0.x; acc.y += v0.y; acc.z += v0.z; acc.w += v0.w;
        acc.x += v1.x; acc.y += v1.y; acc.z += v1.z; acc.w += v1.w;
    }
    if (e < end) {
        int r = rows[e];
        float4 v = *reinterpret_cast<const float4*>(gin + (size_t)r * HIDDEN + f4);
        acc.x += v.x; acc.y += v.y; acc.z += v.z; acc.w += v.w;
    }
    // reduce 4 edge slots (lanes L, L^16, L^32, L^48)
    acc.x += __shfl_xor(acc.x, 16); acc.y += __shfl_xor(acc.y, 16);
    acc.z += __shfl_xor(acc.z, 16); acc.w += __shfl_xor(acc.w, 16);
    acc.x += __shfl_xor(acc.x, 32); acc.y += __shfl_xor(acc.y, 32);
    acc.z += __shfl_xor(acc.z, 32); acc.w += __shfl_xor(acc.w, 32);

    if (grp == 0) {
        float4 h0v = *reinterpret_cast<const float4*>(h0 + (size_t)wid * HIDDEN + f4);
        float4 o;
        o.x = (1.0f - ALPHA) * dn * acc.x + ALPHA * h0v.x;
        o.y = (1.0f - ALPHA) * dn * acc.y + ALPHA * h0v.y;
        o.z = (1.0f - ALPHA) * dn * acc.z + ALPHA * h0v.z;
        o.w = (1.0f - ALPHA) * dn * acc.w + ALPHA * h0v.w;
        if (OUT_G) { o.x *= dn; o.y *= dn; o.z *= dn; o.w *= dn; }
        *reinterpret_cast<float4*>(hout + (size_t)wid * HIDDEN + f4) = o;
    }
}

// ---------------------------------------------------------------------------
// logits = h @ W_pred + b_pred; out = [log_softmax | logits | softmax] flat
__global__ __launch_bounds__(256) void pred_kernel(const float* __restrict__ h,
                                                   const float* __restrict__ Wp,
                                                   const float* __restrict__ bp,
                                                   float* __restrict__ out) {
    __shared__ float Wl[HIDDEN * N_CLASSES];
    __shared__ float bl[N_CLASSES];
    for (int i = threadIdx.x; i < HIDDEN * N_CLASSES; i += 256) Wl[i] = Wp[i];
    if (threadIdx.x < N_CLASSES) bl[threadIdx.x] = bp[threadIdx.x];
    __syncthreads();

    int node = blockIdx.x * 256 + threadIdx.x;
    if (node >= N_NODES) return;

    float acc[N_CLASSES];
#pragma unroll
    for (int c = 0; c < N_CLASSES; ++c) acc[c] = bl[c];

    const float* hr = h + (size_t)node * HIDDEN;
    for (int k = 0; k < HIDDEN; k += 4) {
        float4 hv = *reinterpret_cast<const float4*>(hr + k);
#pragma unroll
        for (int kk = 0; kk < 4; ++kk) {
            float hs = (&hv.x)[kk];
#pragma unroll
            for (int c = 0; c < N_CLASSES; ++c)
                acc[c] += hs * Wl[(k + kk) * N_CLASSES + c];
        }
    }
    float mx = acc[0];
#pragma unroll
    for (int c = 1; c < N_CLASSES; ++c) mx = fmaxf(mx, acc[c]);
    float sum = 0.0f;
    float ex[N_CLASSES];
#pragma unroll
    for (int c = 0; c < N_CLASSES; ++c) { ex[c] = expf(acc[c] - mx); sum += ex[c]; }
    float lse = mx + logf(sum);
    float inv = 1.0f / sum;

    size_t o1 = (size_t)node * N_CLASSES;
#pragma unroll
    for (int c = 0; c < N_CLASSES; ++c) out[o1 + c] = acc[c] - lse;
#pragma unroll
    for (int c = 0; c < N_CLASSES; ++c) out[(size_t)N_NODES * N_CLASSES + o1 + c] = acc[c];
#pragma unroll
    for (int c = 0; c < N_CLASSES; ++c) out[(size_t)2 * N_NODES * N_CLASSES + o1 + c] = ex[c] * inv;
}

// ---------------------------------------------------------------------------
extern "C" void kernel_launch(void* const* d_in, const int* in_sizes, int n_in,
                              void* d_out, int out_size, void* d_ws, size_t ws_size,
                              hipStream_t stream) {
    const float* x       = (const float*)d_in[0];
    const int*   ei      = (const int*)d_in[1];    // [2, E]: rows then cols
    const float* W_embed = (const float*)d_in[2];
    const float* b_embed = (const float*)d_in[3];
    const float* W_pred  = (const float*)d_in[4];
    const float* b_pred  = (const float*)d_in[5];
    float* out = (float*)d_out;

    char* ws = (char*)d_ws;
    size_t off = 0;
    auto alloc = [&](size_t bytes) -> void* {
        void* p = ws + off;
        off += (bytes + 255) & ~(size_t)255;
        return p;
    };
    float* h0      = (float*)alloc((size_t)N_NODES * HIDDEN * 4);
    float* hA      = (float*)alloc((size_t)N_NODES * HIDDEN * 4);   // bpairs aliases this
    float* hB      = (float*)alloc((size_t)N_NODES * HIDDEN * 4);
    int*   csr_row = (int*)  alloc((size_t)NBUCK * CSRCAP * 4);     // gapped CSR
    float* dis     = (float*)alloc((size_t)N_NODES * 4);
    int*   colbeg  = (int*)  alloc((size_t)N_NODES * 4);
    int*   colend  = (int*)  alloc((size_t)N_NODES * 4);
    int*   bcur    = (int*)  alloc((size_t)NGRP * NBUCK * 4);

    // bpairs (22.4 MB) aliases hA (25.6 MB): dead before hop 0 writes hA
    unsigned int* bpairs = (unsigned int*)hA;

    const int* e_row = ei;
    const int* e_col = ei + N_EDGES;

    // --- CSR build: partition into (group,bucket) streams, then per-bucket build
    hipMemsetAsync(bcur, 0, (size_t)NGRP * NBUCK * 4, stream);
    partition_kernel<<<(N_EDGES + 255) / 256, 256, 0, stream>>>(e_row, e_col, bcur, bpairs);
    build_kernel<<<NBUCK, 256, 0, stream>>>(bpairs, bcur, colbeg, colend, dis, csr_row);

    // --- embed (+ rescaled g0 = dis*h0 into hB) ---
    embed_kernel<<<(N_NODES + 255) / 256, 256, 0, stream>>>(x, W_embed, b_embed, dis, h0, hB);

    // --- 10 propagation hops, ping-pong on rescaled features ---
    // in(0)=hB, out(k)= k even ? hA : hB ; final (k=9) writes unscaled h to hB
    const float* gin = hB;
    for (int k = 0; k < K_HOPS; ++k) {
        float* ho = (k & 1) ? hB : hA;
        if (k == K_HOPS - 1)
            hop_kernel<false><<<N_NODES / 4, 256, 0, stream>>>(gin, h0, colbeg, colend, csr_row, dis, ho);
        else
            hop_kernel<true><<<N_NODES / 4, 256, 0, stream>>>(gin, h0, colbeg, colend, csr_row, dis, ho);
        gin = ho;
    }

    // --- prediction head + softmax outputs (reads hB) ---
    pred_kernel<<<(N_NODES + 255) / 256, 256, 0, stream>>>(gin, W_pred, b_pred, out);
}

// Round 6
// 1718.051 us; speedup vs baseline: 1.2784x; 1.0010x over previous
//
#include <hip/hip_runtime.h>

#define N_NODES 100000
#define N_EDGES 3200000
#define F_IN 512
#define HIDDEN 64
#define N_CLASSES 47
#define K_HOPS 10
#define ALPHA 0.1f

#define NBUCK 1563            // ceil(N_NODES / 64) buckets of 64 node ids
#define NGRP 8                // sub-buckets (≈ per-XCD write streams)
#define SUBCAP 448            // capacity per (group,bucket); mean 256, +12 sigma
#define CSRCAP (NGRP * SUBCAP) // csr_row slots reserved per bucket (gapped CSR)

// ---------------------------------------------------------------------------
// Partition edges into (group, bucket) append streams.
// bucket = col >> 6 ; packed word = (col & 63) << 20 | row   (row < 2^17)
__global__ __launch_bounds__(256) void partition_kernel(const int* __restrict__ row,
                                                        const int* __restrict__ col,
                                                        int* __restrict__ bcur,
                                                        unsigned int* __restrict__ bpairs) {
    int e = blockIdx.x * 256 + threadIdx.x;
    if (e >= N_EDGES) return;
    int g = blockIdx.x & (NGRP - 1);
    int c = col[e];
    int b = c >> 6;
    int slot = atomicAdd(&bcur[g * NBUCK + b], 1);
    if (slot < SUBCAP) {
        bpairs[((size_t)g * NBUCK + b) * SUBCAP + slot] =
            (unsigned int)row[e] | ((unsigned int)(c & 63) << 20);
    }
}

// ---------------------------------------------------------------------------
// One block per bucket: count 64 local degrees in LDS, local scan, write
// colbeg/colend/dis and scatter rows into this bucket's contiguous csr region.
__global__ __launch_bounds__(256) void build_kernel(const unsigned int* __restrict__ bpairs,
                                                    const int* __restrict__ bcur,
                                                    int* __restrict__ colbeg,
                                                    int* __restrict__ colend,
                                                    float* __restrict__ dis,
                                                    int* __restrict__ csr_row) {
    __shared__ int lcnt[64];
    __shared__ int lcur[64];
    int b = blockIdx.x;
    int tid = threadIdx.x;
    if (tid < 64) lcnt[tid] = 0;
    __syncthreads();

    for (int g = 0; g < NGRP; ++g) {
        int cg = bcur[g * NBUCK + b];
        if (cg > SUBCAP) cg = SUBCAP;
        const unsigned int* seg = bpairs + ((size_t)g * NBUCK + b) * SUBCAP;
        for (int i = tid; i < cg; i += 256)
            atomicAdd(&lcnt[seg[i] >> 20], 1);
    }
    __syncthreads();

    if (tid == 0) {
        int run = b * CSRCAP;
        for (int j = 0; j < 64; ++j) { lcur[j] = run; run += lcnt[j]; }
    }
    __syncthreads();
    if (tid < 64) {
        int node = b * 64 + tid;
        if (node < N_NODES) {
            colbeg[node] = lcur[tid];
            colend[node] = lcur[tid] + lcnt[tid];
            dis[node] = rsqrtf((float)lcnt[tid] + 1.0f);  // +1 = self loop
        }
    }
    __syncthreads();

    for (int g = 0; g < NGRP; ++g) {
        int cg = bcur[g * NBUCK + b];
        if (cg > SUBCAP) cg = SUBCAP;
        const unsigned int* seg = bpairs + ((size_t)g * NBUCK + b) * SUBCAP;
        for (int i = tid; i < cg; i += 256) {
            unsigned int p = seg[i];
            int slot = atomicAdd(&lcur[p >> 20], 1);
            csr_row[slot] = (int)(p & 0xFFFFFu);
        }
    }
}

// ---------------------------------------------------------------------------
// h0 = relu(x @ W_embed + b_embed); also g0 = dis * h0.
// 2 threads per row (32 cols each) -> 128 rows/block, grid = 782 blocks
// (3 blocks/CU vs 1.5 before: fixes the 15.6% occupancy / latency bound).
__global__ __launch_bounds__(256) void embed_kernel(const float* __restrict__ x,
                                                    const float* __restrict__ W,
                                                    const float* __restrict__ b,
                                                    const float* __restrict__ dis,
                                                    float* __restrict__ h0,
                                                    float* __restrict__ g0) {
    __shared__ float Wl[128 * 64];   // 32 KB K-chunk of W
    int t = threadIdx.x;
    int row = blockIdx.x * 128 + (t >> 1);
    int c0 = (t & 1) * 32;           // column half owned by this thread
    float acc[32];
#pragma unroll
    for (int c = 0; c < 32; ++c) acc[c] = 0.0f;

    for (int kc = 0; kc < F_IN; kc += 128) {
        __syncthreads();
        for (int i = t * 4; i < 128 * 64; i += 256 * 4) {
            *reinterpret_cast<float4*>(Wl + i) =
                *reinterpret_cast<const float4*>(W + (size_t)kc * 64 + i);
        }
        __syncthreads();
        if (row < N_NODES) {
            const float* xr = x + (size_t)row * F_IN + kc;
            for (int k = 0; k < 128; k += 4) {
                float4 xv = *reinterpret_cast<const float4*>(xr + k);
#pragma unroll
                for (int kk = 0; kk < 4; ++kk) {
                    float xs = (&xv.x)[kk];
                    const float* wrow = Wl + (k + kk) * 64 + c0;
#pragma unroll
                    for (int c = 0; c < 32; c += 4) {
                        float4 wv = *reinterpret_cast<const float4*>(wrow + c);
                        acc[c]     += xs * wv.x;
                        acc[c + 1] += xs * wv.y;
                        acc[c + 2] += xs * wv.z;
                        acc[c + 3] += xs * wv.w;
                    }
                }
            }
        }
    }
    if (row < N_NODES) {
        float dn = dis[row];
#pragma unroll
        for (int c = 0; c < 32; c += 4) {
            float4 bv = *reinterpret_cast<const float4*>(b + c0 + c);
            float4 o, g;
            o.x = fmaxf(acc[c]     + bv.x, 0.0f);
            o.y = fmaxf(acc[c + 1] + bv.y, 0.0f);
            o.z = fmaxf(acc[c + 2] + bv.z, 0.0f);
            o.w = fmaxf(acc[c + 3] + bv.w, 0.0f);
            g.x = dn * o.x; g.y = dn * o.y; g.z = dn * o.z; g.w = dn * o.w;
            *reinterpret_cast<float4*>(h0 + (size_t)row * HIDDEN + c0 + c) = o;
            *reinterpret_cast<float4*>(g0 + (size_t)row * HIDDEN + c0 + c) = g;
        }
    }
}

// ---------------------------------------------------------------------------
// One hop on rescaled features g = dis*h:
//   S[n]  = g[n] + sum_{e: col=n} g[row_e]
//   h'[n] = 0.9 * dis[n] * S[n] + 0.1 * h0[n] ;  out = OUT_G ? dis*h' : h'
template <bool OUT_G>
__global__ __launch_bounds__(256) void hop_kernel(const float* __restrict__ gin,
                                                  const float* __restrict__ h0,
                                                  const int* __restrict__ colbeg,
                                                  const int* __restrict__ colend,
                                                  const int* __restrict__ rows,
                                                  const float* __restrict__ dis,
                                                  float* __restrict__ hout) {
    int wid  = (blockIdx.x * 256 + threadIdx.x) >> 6;   // node
    int lane = threadIdx.x & 63;
    int grp  = lane >> 4;            // edge slot 0..3
    int f4   = (lane & 15) << 2;     // feature base

    int beg = colbeg[wid];
    int end = colend[wid];
    float dn = dis[wid];

    float4 acc = make_float4(0.f, 0.f, 0.f, 0.f);
    if (grp == 0) {  // self contribution: + g[n]
        acc = *reinterpret_cast<const float4*>(gin + (size_t)wid * HIDDEN + f4);
    }
    int e = beg + grp;
    for (; e + 4 < end; e += 8) {    // 2 independent gather chains
        int r0 = rows[e];
        int r1 = rows[e + 4];
        float4 v0 = *reinterpret_cast<const float4*>(gin + (size_t)r0 * HIDDEN + f4);
        float4 v1 = *reinterpret_cast<const float4*>(gin + (size_t)r1 * HIDDEN + f4);
        acc.x += v0.x; acc.y += v0.y; acc.z += v0.z; acc.w += v0.w;
        acc.x += v1.x; acc.y += v1.y; acc.z += v1.z; acc.w += v1.w;
    }
    if (e < end) {
        int r = rows[e];
        float4 v = *reinterpret_cast<const float4*>(gin + (size_t)r * HIDDEN + f4);
        acc.x += v.x; acc.y += v.y; acc.z += v.z; acc.w += v.w;
    }
    acc.x += __shfl_xor(acc.x, 16); acc.y += __shfl_xor(acc.y, 16);
    acc.z += __shfl_xor(acc.z, 16); acc.w += __shfl_xor(acc.w, 16);
    acc.x += __shfl_xor(acc.x, 32); acc.y += __shfl_xor(acc.y, 32);
    acc.z += __shfl_xor(acc.z, 32); acc.w += __shfl_xor(acc.w, 32);

    if (grp == 0) {
        float4 h0v = *reinterpret_cast<const float4*>(h0 + (size_t)wid * HIDDEN + f4);
        float4 o;
        o.x = (1.0f - ALPHA) * dn * acc.x + ALPHA * h0v.x;
        o.y = (1.0f - ALPHA) * dn * acc.y + ALPHA * h0v.y;
        o.z = (1.0f - ALPHA) * dn * acc.z + ALPHA * h0v.z;
        o.w = (1.0f - ALPHA) * dn * acc.w + ALPHA * h0v.w;
        if (OUT_G) { o.x *= dn; o.y *= dn; o.z *= dn; o.w *= dn; }
        *reinterpret_cast<float4*>(hout + (size_t)wid * HIDDEN + f4) = o;
    }
}

// ---------------------------------------------------------------------------
// logits = h @ W_pred + b_pred; out = [log_softmax | logits | softmax] flat
__global__ __launch_bounds__(256) void pred_kernel(const float* __restrict__ h,
                                                   const float* __restrict__ Wp,
                                                   const float* __restrict__ bp,
                                                   float* __restrict__ out) {
    __shared__ float Wl[HIDDEN * N_CLASSES];
    __shared__ float bl[N_CLASSES];
    for (int i = threadIdx.x; i < HIDDEN * N_CLASSES; i += 256) Wl[i] = Wp[i];
    if (threadIdx.x < N_CLASSES) bl[threadIdx.x] = bp[threadIdx.x];
    __syncthreads();

    int node = blockIdx.x * 256 + threadIdx.x;
    if (node >= N_NODES) return;

    float acc[N_CLASSES];
#pragma unroll
    for (int c = 0; c < N_CLASSES; ++c) acc[c] = bl[c];

    const float* hr = h + (size_t)node * HIDDEN;
    for (int k = 0; k < HIDDEN; k += 4) {
        float4 hv = *reinterpret_cast<const float4*>(hr + k);
#pragma unroll
        for (int kk = 0; kk < 4; ++kk) {
            float hs = (&hv.x)[kk];
#pragma unroll
            for (int c = 0; c < N_CLASSES; ++c)
                acc[c] += hs * Wl[(k + kk) * N_CLASSES + c];
        }
    }
    float mx = acc[0];
#pragma unroll
    for (int c = 1; c < N_CLASSES; ++c) mx = fmaxf(mx, acc[c]);
    float sum = 0.0f;
    float ex[N_CLASSES];
#pragma unroll
    for (int c = 0; c < N_CLASSES; ++c) { ex[c] = expf(acc[c] - mx); sum += ex[c]; }
    float lse = mx + logf(sum);
    float inv = 1.0f / sum;

    size_t o1 = (size_t)node * N_CLASSES;
#pragma unroll
    for (int c = 0; c < N_CLASSES; ++c) out[o1 + c] = acc[c] - lse;
#pragma unroll
    for (int c = 0; c < N_CLASSES; ++c) out[(size_t)N_NODES * N_CLASSES + o1 + c] = acc[c];
#pragma unroll
    for (int c = 0; c < N_CLASSES; ++c) out[(size_t)2 * N_NODES * N_CLASSES + o1 + c] = ex[c] * inv;
}

// ---------------------------------------------------------------------------
extern "C" void kernel_launch(void* const* d_in, const int* in_sizes, int n_in,
                              void* d_out, int out_size, void* d_ws, size_t ws_size,
                              hipStream_t stream) {
    const float* x       = (const float*)d_in[0];
    const int*   ei      = (const int*)d_in[1];    // [2, E]: rows then cols
    const float* W_embed = (const float*)d_in[2];
    const float* b_embed = (const float*)d_in[3];
    const float* W_pred  = (const float*)d_in[4];
    const float* b_pred  = (const float*)d_in[5];
    float* out = (float*)d_out;

    char* ws = (char*)d_ws;
    size_t off = 0;
    auto alloc = [&](size_t bytes) -> void* {
        void* p = ws + off;
        off += (bytes + 255) & ~(size_t)255;
        return p;
    };
    float* h0      = (float*)alloc((size_t)N_NODES * HIDDEN * 4);
    float* hA      = (float*)alloc((size_t)N_NODES * HIDDEN * 4);   // bpairs aliases this
    float* hB      = (float*)alloc((size_t)N_NODES * HIDDEN * 4);
    int*   csr_row = (int*)  alloc((size_t)NBUCK * CSRCAP * 4);     // gapped CSR
    float* dis     = (float*)alloc((size_t)N_NODES * 4);
    int*   colbeg  = (int*)  alloc((size_t)N_NODES * 4);
    int*   colend  = (int*)  alloc((size_t)N_NODES * 4);
    int*   bcur    = (int*)  alloc((size_t)NGRP * NBUCK * 4);

    // bpairs (22.4 MB) aliases hA (25.6 MB): dead before hop 0 writes hA
    unsigned int* bpairs = (unsigned int*)hA;

    const int* e_row = ei;
    const int* e_col = ei + N_EDGES;

    // --- CSR build ---
    hipMemsetAsync(bcur, 0, (size_t)NGRP * NBUCK * 4, stream);
    partition_kernel<<<(N_EDGES + 255) / 256, 256, 0, stream>>>(e_row, e_col, bcur, bpairs);
    build_kernel<<<NBUCK, 256, 0, stream>>>(bpairs, bcur, colbeg, colend, dis, csr_row);

    // --- embed (+ rescaled g0 = dis*h0 into hB) ---
    embed_kernel<<<(N_NODES + 127) / 128, 256, 0, stream>>>(x, W_embed, b_embed, dis, h0, hB);

    // --- 10 propagation hops, ping-pong on rescaled features ---
    const float* gin = hB;
    for (int k = 0; k < K_HOPS; ++k) {
        float* ho = (k & 1) ? hB : hA;
        if (k == K_HOPS - 1)
            hop_kernel<false><<<N_NODES / 4, 256, 0, stream>>>(gin, h0, colbeg, colend, csr_row, dis, ho);
        else
            hop_kernel<true><<<N_NODES / 4, 256, 0, stream>>>(gin, h0, colbeg, colend, csr_row, dis, ho);
        gin = ho;
    }

    // --- prediction head + softmax outputs (reads hB) ---
    pred_kernel<<<(N_NODES + 255) / 256, 256, 0, stream>>>(gin, W_pred, b_pred, out);
}